// Round 10
// baseline (302.329 us; speedup 1.0000x reference)
//
#include <hip/hip_runtime.h>
#include <hip/hip_bf16.h>
#include <math.h>

#define NPTS 4096
#define KNB 16
#define CAP 384
#define QPB 8     // points (=knn queries) per block
#define PRODS 656 // producer blocks: 512 qkv tiles + 144 pack blocks

typedef __attribute__((ext_vector_type(8))) short bf16x8;
typedef __attribute__((ext_vector_type(4))) float f32x4;
#define MFMA16(a, b, c) __builtin_amdgcn_mfma_f32_16x16x32_bf16(a, b, c, 0, 0, 0)

__device__ __forceinline__ unsigned short f2bf(float f) {
  unsigned int u = __float_as_uint(f);
  unsigned int r = (u + 0x7fffu + ((u >> 16) & 1u)) >> 16;
  return (unsigned short)r;
}
__device__ __forceinline__ float bf2f(unsigned short u) {
  return __uint_as_float((unsigned int)u << 16);
}

// ---------------------------------------------------------------------------
// Kernel "mono": grid 1024 x 256.
//   phase 0 (producers = lowest 656 block ids, deadlock-safe at >=3 blk/CU):
//     bid<512:      qkv 16-row MFMA tile (rows bid*16..+15), signal cnt
//     bid in [512,656): pack w_a1/w_a2/w_p2 -> bf16 B-frag order, signal cnt
//   phase 1 (all blocks): KNN for 8 points (uses only pos; overlaps phase 0)
//   spin until cnt==PRODS (release/acquire via __threadfence + atomics)
//   phase 2 (all blocks): MFMA attention + fc + stats (R9 fused body)
// ---------------------------------------------------------------------------
__global__ __launch_bounds__(256, 4) void mono_kernel(
    const float* __restrict__ x, const float* __restrict__ w_qkv,
    const float* __restrict__ b_qkv, float* __restrict__ qkv,
    const float* __restrict__ w_a1, const float* __restrict__ w_a2,
    const float* __restrict__ w_p2, unsigned short* __restrict__ pk1,
    unsigned short* __restrict__ pk2, unsigned short* __restrict__ pkp,
    const float* __restrict__ pos, const float* __restrict__ w_p1,
    const float* __restrict__ b_p1, const float* __restrict__ b_p2,
    const float* __restrict__ b_a1, const float* __restrict__ b_a2,
    const float* __restrict__ w_fc, const float* __restrict__ b_fc,
    float* __restrict__ y, float* __restrict__ stats,
    unsigned int* __restrict__ cnt) {
  __shared__ __align__(16) char smem[38400];
  __shared__ int s_idx[128];

  int tid = threadIdx.x, lane = tid & 63, w = tid >> 6;
  int m = lane & 15, quad = lane >> 4;
  int bid = blockIdx.x;
  int g0 = bid * QPB;
  int b = g0 >> 12;
  const float* posb = pos + (size_t)b * NPTS * 3;

  // ======================= phase 0: producers =======================
  if (bid < 512) {
    // qkv tile: rows r0..r0+15; wave w handles col-tiles 3w..3w+2
    int r0 = bid * 16;
    const float* xr = x + (size_t)(r0 + m) * 64;
    float xa[8], xb[8];
    *(float4*)&xa[0] = *(const float4*)(xr + quad * 8);
    *(float4*)&xa[4] = *(const float4*)(xr + quad * 8 + 4);
    *(float4*)&xb[0] = *(const float4*)(xr + 32 + quad * 8);
    *(float4*)&xb[4] = *(const float4*)(xr + 32 + quad * 8 + 4);
    bf16x8 a0, a1;
#pragma unroll
    for (int j = 0; j < 8; ++j) {
      a0[j] = (short)f2bf(xa[j]);
      a1[j] = (short)f2bf(xb[j]);
    }
#pragma unroll
    for (int ntl = 0; ntl < 3; ++ntl) {
      int nt = w * 3 + ntl;
      int n = nt * 16 + m;
      int k0 = quad * 8;
      bf16x8 b0, b1;
#pragma unroll
      for (int j = 0; j < 8; ++j) {
        b0[j] = (short)f2bf(w_qkv[(size_t)(k0 + j) * 192 + n]);
        b1[j] = (short)f2bf(w_qkv[(size_t)(32 + k0 + j) * 192 + n]);
      }
      f32x4 acc = {0.f, 0.f, 0.f, 0.f};
      acc = MFMA16(a0, b0, acc);
      acc = MFMA16(a1, b1, acc);
      float bb = b_qkv[n];
#pragma unroll
      for (int i = 0; i < 4; ++i)
        qkv[(size_t)(r0 + quad * 4 + i) * 192 + n] = acc[i] + bb;
    }
    __threadfence();
    __syncthreads();
    if (tid == 0) atomicAdd(cnt, 1u);
  } else if (bid < PRODS) {
    int e = (bid - 512) * 256 + tid;
    if (e < 16384) {  // w_a1 [64][256]: KS=2, NT=16
      int j = e & 7, ln = (e >> 3) & 63, t = e >> 9;
      int ks = t & 1, nt = t >> 1;
      int k = ks * 32 + ((ln >> 4) << 3) + j, n = nt * 16 + (ln & 15);
      pk1[e] = f2bf(w_a1[k * 256 + n]);
    } else if (e < 32768) {  // w_a2 [256][64]: KS=8, NT=4
      int e2 = e - 16384;
      int j = e2 & 7, ln = (e2 >> 3) & 63, t = e2 >> 9;
      int ks = t & 7, nt = t >> 3;
      int k = ks * 32 + ((ln >> 4) << 3) + j, n = nt * 16 + (ln & 15);
      pk2[e2] = f2bf(w_a2[k * 64 + n]);
    } else if (e < 36864) {  // w_p2 [64][64]: KS=2, NT=4
      int e3 = e - 32768;
      int j = e3 & 7, ln = (e3 >> 3) & 63, t = e3 >> 9;
      int ks = t & 1, nt = t >> 1;
      int k = ks * 32 + ((ln >> 4) << 3) + j, n = nt * 16 + (ln & 15);
      pkp[e3] = f2bf(w_p2[k * 64 + n]);
    }
    __threadfence();
    __syncthreads();
    if (tid == 0) atomicAdd(cnt, 1u);
  }

  // ======================= phase 1: KNN (pos only) =======================
  {
    unsigned int(*cbits)[CAP] = (unsigned int(*)[CAP])smem;            // 12288
    int(*cidx)[CAP] = (int(*)[CAP])(smem + 12288);                     // 12288
    unsigned long long* wmin = (unsigned long long*)(smem + 25088);
    float* sretry = (float*)(smem + 25120);
    unsigned int* scnt = (unsigned int*)(smem + 25152);
    unsigned long long* sprev = (unsigned long long*)(smem + 25184);
    int* sany = (int*)(smem + 25192);

    float qx[QPB], qy[QPB], qz[QPB];
#pragma unroll
    for (int q = 0; q < QPB; ++q) {
      int i = (g0 + q) & (NPTS - 1);
      qx[q] = posb[i * 3 + 0];
      qy[q] = posb[i * 3 + 1];
      qz[q] = posb[i * 3 + 2];
    }
    __syncthreads();  // smem fresh for all (incl. producer blocks)
    if (tid < QPB) scnt[tid] = 0;
    if (tid == 0) sany[0] = 0;
    __syncthreads();

    const float T2 = 0.015625f;  // d < 0.125; expected count ~33
    for (int c = 0; c < NPTS / 256; ++c) {
      int j = c * 256 + tid;
      int j3 = j * 3;
      float px = posb[j3 + 0], py = posb[j3 + 1], pz = posb[j3 + 2];
#pragma unroll
      for (int q = 0; q < QPB; ++q) {
        float dx = qx[q] - px, dy = qy[q] - py, dz = qz[q] - pz;
        float d2 = fmaf(dz, dz, fmaf(dy, dy, dx * dx));
        if (d2 < T2) {
          unsigned int p = atomicAdd(&scnt[q], 1u);
          if (p < CAP) {
            cbits[q][p] = __float_as_uint(d2);
            cidx[q][p] = j;
          }
        }
      }
    }
    __syncthreads();

    if (tid < QPB) {
      int q = tid;
      unsigned int n = scnt[q];
      float nt = 0.f;
      if (n < KNB) nt = 0.0625f;
      else if (n > CAP) nt = 0.00390625f;
      sretry[q] = nt;
      if (nt != 0.f) {
        scnt[q] = 0;
        sany[0] = 1;
      }
    }
    __syncthreads();

    if (sany[0]) {  // rare; block-uniform
      float tr[QPB];
#pragma unroll
      for (int q = 0; q < QPB; ++q) tr[q] = sretry[q];
      for (int c = 0; c < NPTS / 256; ++c) {
        int j = c * 256 + tid;
        int j3 = j * 3;
        float px = posb[j3 + 0], py = posb[j3 + 1], pz = posb[j3 + 2];
#pragma unroll
        for (int q = 0; q < QPB; ++q) {
          if (tr[q] != 0.f) {
            float dx = qx[q] - px, dy = qy[q] - py, dz = qz[q] - pz;
            float d2 = fmaf(dz, dz, fmaf(dy, dy, dx * dx));
            if (d2 < tr[q]) {
              unsigned int p = atomicAdd(&scnt[q], 1u);
              if (p < CAP) {
                cbits[q][p] = __float_as_uint(d2);
                cidx[q][p] = j;
              }
            }
          }
        }
      }
      __syncthreads();
    }

    for (int qq = 0; qq < 2; ++qq) {
      int q = w * 2 + qq;
      int L = (int)scnt[q];
      if (L >= KNB && L <= CAP) {
        for (int i = lane; i < L; i += 64) {
          unsigned long long ki = ((unsigned long long)cbits[q][i] << 32) |
                                  (unsigned int)cidx[q][i];
          int rank = 0;
          for (int mm = 0; mm < L; ++mm) {
            unsigned long long km = ((unsigned long long)cbits[q][mm] << 32) |
                                    (unsigned int)cidx[q][mm];
            rank += km < ki;
          }
          if (rank < KNB) s_idx[q * KNB + rank] = cidx[q][i];
        }
      }
    }
    __syncthreads();

    for (int q = 0; q < QPB; ++q) {
      unsigned int n = scnt[q];
      if (n < KNB || n > CAP) {  // pathological exact fallback
        unsigned long long prev = 0ull;
        for (int r = 0; r < KNB; ++r) {
          unsigned long long best = ~0ull;
          for (int c = 0; c < NPTS / 256; ++c) {
            int j = c * 256 + tid;
            float dx = qx[q] - posb[j * 3 + 0];
            float dy = qy[q] - posb[j * 3 + 1];
            float dz = qz[q] - posb[j * 3 + 2];
            float d2 = fmaf(dz, dz, fmaf(dy, dy, dx * dx));
            unsigned long long key =
                ((unsigned long long)__float_as_uint(d2) << 32) |
                (unsigned int)j;
            bool ok = (r == 0) || (key > prev);
            best = (ok && key < best) ? key : best;
          }
#pragma unroll
          for (int off = 32; off > 0; off >>= 1) {
            unsigned long long o = __shfl_down(best, off);
            best = best < o ? best : o;
          }
          if (lane == 0) wmin[w] = best;
          __syncthreads();
          if (tid == 0) {
            unsigned long long m0 = wmin[0], m1 = wmin[1];
            unsigned long long m2 = wmin[2], m3 = wmin[3];
            unsigned long long a = m0 < m1 ? m0 : m1;
            unsigned long long d = m2 < m3 ? m2 : m3;
            a = a < d ? a : d;
            s_idx[q * KNB + r] = (int)(unsigned int)a;
            sprev[0] = a;
          }
          __syncthreads();
          prev = sprev[0];
          __syncthreads();
        }
      }
    }
  }

  // ============ wait for qkv + packed weights (acquire) ============
  if (tid == 0) {
    while (atomicAdd(cnt, 0u) < PRODS) __builtin_amdgcn_s_sleep(4);
  }
  __syncthreads();
  __threadfence();

  // ======================= phase 2: attention =======================
  unsigned short(*region)[72] = (unsigned short(*)[72])smem;        // 18432
  unsigned short(*s_v)[72] = (unsigned short(*)[72])(smem + 18432); // 18432
  float(*s_rel)[32][3] = (float(*)[32][3])(smem + 36864);           // 1536

  if (lane < 32) {
    int row = 32 * w + lane;
    int p = lane >> 4;
    int g = g0 + 2 * w + p;
    int jb = (b << 12) | s_idx[row];
    s_rel[w][lane][0] = pos[(size_t)g * 3 + 0] - pos[(size_t)jb * 3 + 0];
    s_rel[w][lane][1] = pos[(size_t)g * 3 + 1] - pos[(size_t)jb * 3 + 1];
    s_rel[w][lane][2] = pos[(size_t)g * 3 + 2] - pos[(size_t)jb * 3 + 2];
  }
  for (int rl = 0; rl < 32; ++rl) {
    int row = 32 * w + rl;
    int jb = (b << 12) | s_idx[row];
    s_v[row][lane] = f2bf(qkv[(size_t)jb * 192 + 128 + lane]);
  }

  // e = relu(rel @ w_p1 + b_p1) -> region (s_e), wave rows
  {
    float w0 = w_p1[lane], w1 = w_p1[64 + lane], w2 = w_p1[128 + lane];
    float bp = b_p1[lane];
    for (int rl = 0; rl < 32; ++rl) {
      int row = 32 * w + rl;
      float rx = s_rel[w][rl][0], ry = s_rel[w][rl][1], rz = s_rel[w][rl][2];
      float e = fmaf(rz, w2, fmaf(ry, w1, fmaf(rx, w0, bp)));
      region[row][lane] = f2bf(fmaxf(e, 0.f));
    }
  }

  // pe MFMA + h epilogue; s_h overwrites s_e (frags in regs first)
  {
    bf16x8 ea0[2], ea1[2];
#pragma unroll
    for (int p = 0; p < 2; ++p) {
      ea0[p] = *(const bf16x8*)&region[32 * w + 16 * p + m][quad * 8];
      ea1[p] = *(const bf16x8*)&region[32 * w + 16 * p + m][32 + quad * 8];
    }
#pragma unroll
    for (int nt = 0; nt < 4; ++nt) {
      bf16x8 b0 = *(const bf16x8*)(pkp + ((size_t)(nt * 2 + 0) * 64 + lane) * 8);
      bf16x8 b1 = *(const bf16x8*)(pkp + ((size_t)(nt * 2 + 1) * 64 + lane) * 8);
      int col = nt * 16 + m;
      float bp2 = b_p2[col];
#pragma unroll
      for (int p = 0; p < 2; ++p) {
        f32x4 acc = {0.f, 0.f, 0.f, 0.f};
        acc = MFMA16(ea0[p], b0, acc);
        acc = MFMA16(ea1[p], b1, acc);
        int g = g0 + 2 * w + p;
        float qv = qkv[(size_t)g * 192 + col];
#pragma unroll
        for (int i = 0; i < 4; ++i) {
          int row = 32 * w + 16 * p + quad * 4 + i;
          int jb = (b << 12) | s_idx[row];
          float kv = qkv[(size_t)jb * 192 + 64 + col];
          region[row][col] = f2bf(qv - kv + acc[i] + bp2);  // s_h
        }
      }
    }
  }

  // chunked GEMM1 -> s_tc (aliases own s_h rows) -> GEMM2 acc
  bf16x8 ha0[2], ha1[2];
#pragma unroll
  for (int p = 0; p < 2; ++p) {
    ha0[p] = *(const bf16x8*)&region[32 * w + 16 * p + m][quad * 8];
    ha1[p] = *(const bf16x8*)&region[32 * w + 16 * p + m][32 + quad * 8];
  }
  f32x4 acc2[2][4];
#pragma unroll
  for (int p = 0; p < 2; ++p)
#pragma unroll
    for (int nt2 = 0; nt2 < 4; ++nt2) acc2[p][nt2] = (f32x4){0.f, 0.f, 0.f, 0.f};

  unsigned short(*s_tc)[72] = (unsigned short(*)[72])(smem + w * 4608);

#pragma unroll
  for (int c = 0; c < 4; ++c) {
#pragma unroll
    for (int ntc = 0; ntc < 4; ++ntc) {
      int nt = 4 * c + ntc;
      bf16x8 b0 = *(const bf16x8*)(pk1 + ((size_t)(nt * 2 + 0) * 64 + lane) * 8);
      bf16x8 b1 = *(const bf16x8*)(pk1 + ((size_t)(nt * 2 + 1) * 64 + lane) * 8);
      int coll = ntc * 16 + m;
      float ba = b_a1[nt * 16 + m];
#pragma unroll
      for (int p = 0; p < 2; ++p) {
        f32x4 t = {0.f, 0.f, 0.f, 0.f};
        t = MFMA16(ha0[p], b0, t);
        t = MFMA16(ha1[p], b1, t);
#pragma unroll
        for (int i = 0; i < 4; ++i)
          s_tc[16 * p + quad * 4 + i][coll] = f2bf(fmaxf(t[i] + ba, 0.f));
      }
    }
#pragma unroll
    for (int sub = 0; sub < 2; ++sub) {
      int ks = c * 2 + sub;
      bf16x8 a[2];
#pragma unroll
      for (int p = 0; p < 2; ++p)
        a[p] = *(const bf16x8*)&s_tc[16 * p + m][sub * 32 + quad * 8];
#pragma unroll
      for (int nt2 = 0; nt2 < 4; ++nt2) {
        bf16x8 bb =
            *(const bf16x8*)(pk2 + ((size_t)(nt2 * 8 + ks) * 64 + lane) * 8);
#pragma unroll
        for (int p = 0; p < 2; ++p) acc2[p][nt2] = MFMA16(a[p], bb, acc2[p][nt2]);
      }
    }
  }

  // softmax over k (quad shuffles) + v-weighted sum
  float ba2[4];
#pragma unroll
  for (int nt2 = 0; nt2 < 4; ++nt2) ba2[nt2] = b_a2[nt2 * 16 + m];
  float aggv[2][4];
#pragma unroll
  for (int p = 0; p < 2; ++p) {
#pragma unroll
    for (int nt2 = 0; nt2 < 4; ++nt2) {
      float sc[4];
#pragma unroll
      for (int i = 0; i < 4; ++i) sc[i] = acc2[p][nt2][i] + ba2[nt2];
      float mx = fmaxf(fmaxf(sc[0], sc[1]), fmaxf(sc[2], sc[3]));
      mx = fmaxf(mx, __shfl_xor(mx, 16));
      mx = fmaxf(mx, __shfl_xor(mx, 32));
      float ex[4], ss = 0.f;
#pragma unroll
      for (int i = 0; i < 4; ++i) {
        ex[i] = exp2f((sc[i] - mx) * 1.4426950408889634f);
        ss += ex[i];
      }
      ss += __shfl_xor(ss, 16);
      ss += __shfl_xor(ss, 32);
      int col = nt2 * 16 + m;
      float nu = 0.f;
#pragma unroll
      for (int i = 0; i < 4; ++i) {
        int row = 32 * w + 16 * p + quad * 4 + i;
        nu = fmaf(ex[i], bf2f(s_v[row][col]), nu);
      }
      nu += __shfl_xor(nu, 16);
      nu += __shfl_xor(nu, 32);
      aggv[p][nt2] = nu / ss;
    }
  }
  __syncthreads();  // all waves done with region -> reuse for agg/red

  float* s_agg = (float*)smem;  // [8][64]
  if (quad == 0) {
#pragma unroll
    for (int p = 0; p < 2; ++p)
#pragma unroll
      for (int nt2 = 0; nt2 < 4; ++nt2)
        s_agg[(2 * w + p) * 64 + nt2 * 16 + m] = aggv[p][nt2];
  }
  __syncthreads();

  // fc: thread (r=w, c=lane) handles rows w and w+4
  {
    int c = lane, r = w;
    float acc0 = b_fc[c], acc1 = b_fc[c];
    for (int d = 0; d < 64; ++d) {
      float wv = w_fc[d * 64 + c];
      acc0 = fmaf(s_agg[r * 64 + d], wv, acc0);
      acc1 = fmaf(s_agg[(r + 4) * 64 + d], wv, acc1);
    }
    y[(size_t)(g0 + r) * 64 + c] = acc0;
    y[(size_t)(g0 + r + 4) * 64 + c] = acc1;
    float* s_red = (float*)(smem + 2048);
    float* s_red2 = (float*)(smem + 3072);
    s_red[w * 64 + c] = acc0 + acc1;
    s_red2[w * 64 + c] = acc0 * acc0 + acc1 * acc1;
  }
  __syncthreads();
  if (tid < 64) {
    float* s_red = (float*)(smem + 2048);
    float* s_red2 = (float*)(smem + 3072);
    float s = s_red[tid] + s_red[64 + tid] + s_red[128 + tid] + s_red[192 + tid];
    float s2 =
        s_red2[tid] + s_red2[64 + tid] + s_red2[128 + tid] + s_red2[192 + tid];
    atomicAdd(&stats[tid], s);
    atomicAdd(&stats[64 + tid], s2);
  }
}

// ---------------------------------------------------------------------------
// Kernel "bn": BN (batch stats) + relu + residual.
// ---------------------------------------------------------------------------
__global__ __launch_bounds__(256) void bn_kernel(
    const float* __restrict__ y, const float* __restrict__ x,
    const float* __restrict__ stats, const float* __restrict__ gamma,
    const float* __restrict__ beta, float* __restrict__ out) {
  size_t o = (size_t)blockIdx.x * 256 + threadIdx.x;
  int c = (int)(o & 63);
  const float inv_n = 1.f / 8192.f;
  float mean = stats[c] * inv_n;
  float var = stats[64 + c] * inv_n - mean * mean;
  float inv = rsqrtf(var + 1e-5f);
  float v = (y[o] - mean) * inv * gamma[c] + beta[c];
  out[o] = fmaxf(v, 0.f) + x[o];
}

// ---------------------------------------------------------------------------
extern "C" void kernel_launch(void* const* d_in, const int* in_sizes, int n_in,
                              void* d_out, int out_size, void* d_ws,
                              size_t ws_size, hipStream_t stream) {
  const float* x = (const float*)d_in[0];
  const float* pos = (const float*)d_in[1];
  const float* w_qkv = (const float*)d_in[2];
  const float* b_qkv = (const float*)d_in[3];
  const float* w_p1 = (const float*)d_in[4];
  const float* b_p1 = (const float*)d_in[5];
  const float* w_p2 = (const float*)d_in[6];
  const float* b_p2 = (const float*)d_in[7];
  const float* w_a1 = (const float*)d_in[8];
  const float* b_a1 = (const float*)d_in[9];
  const float* w_a2 = (const float*)d_in[10];
  const float* b_a2 = (const float*)d_in[11];
  const float* w_fc = (const float*)d_in[12];
  const float* b_fc = (const float*)d_in[13];
  const float* gamma = (const float*)d_in[14];
  const float* beta = (const float*)d_in[15];

  char* ws = (char*)d_ws;
  float* qkv = (float*)(ws + 0);                           // 6291456 B
  float* y = (float*)(ws + 8912896);                       // 2097152 B
  float* stats = (float*)(ws + 11010048);                  // 512 B
  unsigned int* cnt = (unsigned int*)(ws + 11010560);      // 4 B (pad to 576)
  unsigned short* pk1 = (unsigned short*)(ws + 11010624);  // 32768 B
  unsigned short* pk2 = (unsigned short*)(ws + 11043392);  // 32768 B
  unsigned short* pkp = (unsigned short*)(ws + 11076160);  // 8192 B

  hipMemsetAsync(ws + 11010048, 0, 576, stream);  // stats + cnt
  hipLaunchKernelGGL(mono_kernel, dim3(1024), dim3(256), 0, stream, x, w_qkv,
                     b_qkv, qkv, w_a1, w_a2, w_p2, pk1, pk2, pkp, pos, w_p1,
                     b_p1, b_p2, b_a1, b_a2, w_fc, b_fc, y, stats, cnt);
  hipLaunchKernelGGL(bn_kernel, dim3(2048), dim3(256), 0, stream, y, x, stats,
                     gamma, beta, (float*)d_out);
}

// Round 11
// 163.025 us; speedup vs baseline: 1.8545x; 1.8545x over previous
//
#include <hip/hip_runtime.h>
#include <hip/hip_bf16.h>
#include <math.h>

#define NPTS 4096
#define KNB 16
#define CAP 384
#define QPB 8   // points (=knn queries) per block

typedef __attribute__((ext_vector_type(8))) short bf16x8;
typedef __attribute__((ext_vector_type(4))) float f32x4;
#define MFMA16(a, b, c) __builtin_amdgcn_mfma_f32_16x16x32_bf16(a, b, c, 0, 0, 0)

__device__ __forceinline__ unsigned short f2bf(float f) {
  unsigned int u = __float_as_uint(f);
  unsigned int r = (u + 0x7fffu + ((u >> 16) & 1u)) >> 16;
  return (unsigned short)r;
}

// ---------------------------------------------------------------------------
// Kernel 1 "qkv_pack":
//   blocks [0,128)   qkv = x @ w_qkv + b_qkv via MFMA (64 rows/block, no LDS)
//   blocks [128,272) pack w_a1/w_a2/w_p2 -> bf16 MFMA B-frag order
//   block 272        zero stats
// ---------------------------------------------------------------------------
__global__ __launch_bounds__(256) void qkv_pack_kernel(
    const float* __restrict__ x, const float* __restrict__ w_qkv,
    const float* __restrict__ b_qkv, float* __restrict__ qkv,
    const float* __restrict__ w_a1, const float* __restrict__ w_a2,
    const float* __restrict__ w_p2, unsigned short* __restrict__ pk1,
    unsigned short* __restrict__ pk2, unsigned short* __restrict__ pkp,
    float* __restrict__ stats) {
  int tid = threadIdx.x, bid = blockIdx.x;

  if (bid == 272) {
    if (tid < 128) stats[tid] = 0.f;
    return;
  }
  if (bid >= 128) {
    int e = (bid - 128) * 256 + tid;
    if (e < 16384) {  // w_a1 [64][256]: KS=2, NT=16
      int j = e & 7, lane = (e >> 3) & 63, t = e >> 9;
      int ks = t & 1, nt = t >> 1;
      int k = ks * 32 + ((lane >> 4) << 3) + j, n = nt * 16 + (lane & 15);
      pk1[e] = f2bf(w_a1[k * 256 + n]);
    } else if (e < 32768) {  // w_a2 [256][64]: KS=8, NT=4
      int e2 = e - 16384;
      int j = e2 & 7, lane = (e2 >> 3) & 63, t = e2 >> 9;
      int ks = t & 7, nt = t >> 3;
      int k = ks * 32 + ((lane >> 4) << 3) + j, n = nt * 16 + (lane & 15);
      pk2[e2] = f2bf(w_a2[k * 64 + n]);
    } else if (e < 36864) {  // w_p2 [64][64]: KS=2, NT=4
      int e3 = e - 32768;
      int j = e3 & 7, lane = (e3 >> 3) & 63, t = e3 >> 9;
      int ks = t & 1, nt = t >> 1;
      int k = ks * 32 + ((lane >> 4) << 3) + j, n = nt * 16 + (lane & 15);
      pkp[e3] = f2bf(w_p2[k * 64 + n]);
    }
    return;
  }

  // qkv MFMA: wave w -> rows r0w..r0w+15
  int lane = tid & 63, w = tid >> 6;
  int m = lane & 15, quad = lane >> 4;
  int r0w = bid * 64 + w * 16;

  const float* xr = x + (size_t)(r0w + m) * 64;
  float xa[8], xb[8];
  *(float4*)&xa[0] = *(const float4*)(xr + quad * 8);
  *(float4*)&xa[4] = *(const float4*)(xr + quad * 8 + 4);
  *(float4*)&xb[0] = *(const float4*)(xr + 32 + quad * 8);
  *(float4*)&xb[4] = *(const float4*)(xr + 32 + quad * 8 + 4);
  bf16x8 a0, a1;
#pragma unroll
  for (int j = 0; j < 8; ++j) {
    a0[j] = (short)f2bf(xa[j]);
    a1[j] = (short)f2bf(xb[j]);
  }

#pragma unroll 4
  for (int nt = 0; nt < 12; ++nt) {
    int n = nt * 16 + m;
    int k0 = quad * 8;
    bf16x8 b0, b1;
#pragma unroll
    for (int j = 0; j < 8; ++j) {
      b0[j] = (short)f2bf(w_qkv[(size_t)(k0 + j) * 192 + n]);
      b1[j] = (short)f2bf(w_qkv[(size_t)(32 + k0 + j) * 192 + n]);
    }
    f32x4 acc = {0.f, 0.f, 0.f, 0.f};
    acc = MFMA16(a0, b0, acc);
    acc = MFMA16(a1, b1, acc);
    float bb = b_qkv[n];
#pragma unroll
    for (int i = 0; i < 4; ++i)
      qkv[(size_t)(r0w + quad * 4 + i) * 192 + n] = acc[i] + bb;
  }
}

// ---------------------------------------------------------------------------
// Kernel 2 "fused" (v2): per block = 8 points. One-pass KNN -> s_idx, then
// MFMA attention + fc + stats. LDS ~25.7 KB (s_v removed; v prefetched into
// 32 VGPRs after phase3, latency hidden behind GEMM1/2) -> 5+ blocks/CU.
// __launch_bounds__(256,5) pins >=5 waves/SIMD.
// ---------------------------------------------------------------------------
__global__ __launch_bounds__(256, 5) void fused_kernel(
    const float* __restrict__ qkv, const float* __restrict__ pos,
    const unsigned short* __restrict__ pk1,
    const unsigned short* __restrict__ pk2,
    const unsigned short* __restrict__ pkp, const float* __restrict__ w_p1,
    const float* __restrict__ b_p1, const float* __restrict__ b_p2,
    const float* __restrict__ b_a1, const float* __restrict__ b_a2,
    const float* __restrict__ w_fc, const float* __restrict__ b_fc,
    float* __restrict__ y, float* __restrict__ stats) {
  __shared__ __align__(16) char smem[25216];
  __shared__ int s_idx[128];

  int tid = threadIdx.x, lane = tid & 63, w = tid >> 6;
  int m = lane & 15, quad = lane >> 4;
  int g0 = blockIdx.x * QPB;
  int b = g0 >> 12;
  const float* posb = pos + (size_t)b * NPTS * 3;

  // ======================= KNN phase =======================
  {
    unsigned int(*cbits)[CAP] = (unsigned int(*)[CAP])smem;            // 12288
    int(*cidx)[CAP] = (int(*)[CAP])(smem + 12288);                     // 12288
    unsigned long long* wmin = (unsigned long long*)(smem + 24576);    // 32
    float* sretry = (float*)(smem + 24608);                            // 32
    unsigned int* scnt = (unsigned int*)(smem + 24640);                // 32
    unsigned long long* sprev = (unsigned long long*)(smem + 24672);   // 8
    int* sany = (int*)(smem + 24680);                                  // 4

    float qx[QPB], qy[QPB], qz[QPB];
#pragma unroll
    for (int q = 0; q < QPB; ++q) {
      int i = (g0 + q) & (NPTS - 1);
      qx[q] = posb[i * 3 + 0];
      qy[q] = posb[i * 3 + 1];
      qz[q] = posb[i * 3 + 2];
    }
    if (tid < QPB) scnt[tid] = 0;
    if (tid == 0) sany[0] = 0;
    __syncthreads();

    const float T2 = 0.015625f;  // d < 0.125; expected count ~33
    for (int c = 0; c < NPTS / 256; ++c) {
      int j = c * 256 + tid;
      int j3 = j * 3;
      float px = posb[j3 + 0], py = posb[j3 + 1], pz = posb[j3 + 2];
#pragma unroll
      for (int q = 0; q < QPB; ++q) {
        float dx = qx[q] - px, dy = qy[q] - py, dz = qz[q] - pz;
        float d2 = fmaf(dz, dz, fmaf(dy, dy, dx * dx));
        bool hit = d2 < T2;
        unsigned long long mask = __ballot(hit);
        if (mask) {  // wave-uniform skip (~60% of iterations have no hits)
          if (hit) {
            unsigned int p = atomicAdd(&scnt[q], 1u);
            if (p < CAP) {
              cbits[q][p] = __float_as_uint(d2);
              cidx[q][p] = j;
            }
          }
        }
      }
    }
    __syncthreads();

    if (tid < QPB) {
      int q = tid;
      unsigned int n = scnt[q];
      float nt = 0.f;
      if (n < KNB) nt = 0.0625f;            // widen: d < 0.25
      else if (n > CAP) nt = 0.00390625f;   // narrow: d < 0.0625
      sretry[q] = nt;
      if (nt != 0.f) {
        scnt[q] = 0;
        sany[0] = 1;
      }
    }
    __syncthreads();

    if (sany[0]) {  // rare; block-uniform
      float tr[QPB];
#pragma unroll
      for (int q = 0; q < QPB; ++q) tr[q] = sretry[q];
      for (int c = 0; c < NPTS / 256; ++c) {
        int j = c * 256 + tid;
        int j3 = j * 3;
        float px = posb[j3 + 0], py = posb[j3 + 1], pz = posb[j3 + 2];
#pragma unroll
        for (int q = 0; q < QPB; ++q) {
          if (tr[q] != 0.f) {
            float dx = qx[q] - px, dy = qy[q] - py, dz = qz[q] - pz;
            float d2 = fmaf(dz, dz, fmaf(dy, dy, dx * dx));
            bool hit = d2 < tr[q];
            unsigned long long mask = __ballot(hit);
            if (mask) {
              if (hit) {
                unsigned int p = atomicAdd(&scnt[q], 1u);
                if (p < CAP) {
                  cbits[q][p] = __float_as_uint(d2);
                  cidx[q][p] = j;
                }
              }
            }
          }
        }
      }
      __syncthreads();
    }

    // rank selection -> s_idx[q*16+rank]; wave w handles queries 2w, 2w+1
    for (int qq = 0; qq < 2; ++qq) {
      int q = w * 2 + qq;
      int L = (int)scnt[q];
      if (L >= KNB && L <= CAP) {
        for (int i = lane; i < L; i += 64) {
          unsigned long long ki = ((unsigned long long)cbits[q][i] << 32) |
                                  (unsigned int)cidx[q][i];
          int rank = 0;
          for (int mm = 0; mm < L; ++mm) {
            unsigned long long km = ((unsigned long long)cbits[q][mm] << 32) |
                                    (unsigned int)cidx[q][mm];
            rank += km < ki;
          }
          if (rank < KNB) s_idx[q * KNB + rank] = cidx[q][i];
        }
      }
    }
    __syncthreads();

    // exact fallback (block-uniform branch; pathological only)
    for (int q = 0; q < QPB; ++q) {
      unsigned int n = scnt[q];
      if (n < KNB || n > CAP) {
        unsigned long long prev = 0ull;
        for (int r = 0; r < KNB; ++r) {
          unsigned long long best = ~0ull;
          for (int c = 0; c < NPTS / 256; ++c) {
            int j = c * 256 + tid;
            float dx = qx[q] - posb[j * 3 + 0];
            float dy = qy[q] - posb[j * 3 + 1];
            float dz = qz[q] - posb[j * 3 + 2];
            float d2 = fmaf(dz, dz, fmaf(dy, dy, dx * dx));
            unsigned long long key =
                ((unsigned long long)__float_as_uint(d2) << 32) |
                (unsigned int)j;
            bool ok = (r == 0) || (key > prev);
            best = (ok && key < best) ? key : best;
          }
#pragma unroll
          for (int off = 32; off > 0; off >>= 1) {
            unsigned long long o = __shfl_down(best, off);
            best = best < o ? best : o;
          }
          if (lane == 0) wmin[w] = best;
          __syncthreads();
          if (tid == 0) {
            unsigned long long m0 = wmin[0], m1 = wmin[1];
            unsigned long long m2 = wmin[2], m3 = wmin[3];
            unsigned long long a = m0 < m1 ? m0 : m1;
            unsigned long long d = m2 < m3 ? m2 : m3;
            a = a < d ? a : d;
            s_idx[q * KNB + r] = (int)(unsigned int)a;
            sprev[0] = a;
          }
          __syncthreads();
          prev = sprev[0];
          __syncthreads();
        }
      }
    }
  }
  __syncthreads();  // knn scratch dead; s_idx valid

  // ======================= attention phase =======================
  unsigned short(*region)[72] = (unsigned short(*)[72])smem;        // 18432
  float(*s_rel)[32][3] = (float(*)[32][3])(smem + 18432);           // 1536

  // staging: rel (parallel 32-lane gather)
  if (lane < 32) {
    int row = 32 * w + lane;
    int p = lane >> 4;
    int g = g0 + 2 * w + p;
    int jb = (b << 12) | s_idx[row];
    s_rel[w][lane][0] = pos[(size_t)g * 3 + 0] - pos[(size_t)jb * 3 + 0];
    s_rel[w][lane][1] = pos[(size_t)g * 3 + 1] - pos[(size_t)jb * 3 + 1];
    s_rel[w][lane][2] = pos[(size_t)g * 3 + 2] - pos[(size_t)jb * 3 + 2];
  }

  // phase2: e = relu(rel @ w_p1 + b_p1) -> region (s_e), wave rows
  {
    float w0 = w_p1[lane], w1 = w_p1[64 + lane], w2 = w_p1[128 + lane];
    float bp = b_p1[lane];
    for (int rl = 0; rl < 32; ++rl) {
      int row = 32 * w + rl;
      float rx = s_rel[w][rl][0], ry = s_rel[w][rl][1], rz = s_rel[w][rl][2];
      float e = fmaf(rz, w2, fmaf(ry, w1, fmaf(rx, w0, bp)));
      region[row][lane] = f2bf(fmaxf(e, 0.f));
    }
  }

  // phase3: pe MFMA + h epilogue; s_h overwrites s_e (frags in regs first)
  {
    bf16x8 ea0[2], ea1[2];
#pragma unroll
    for (int p = 0; p < 2; ++p) {
      ea0[p] = *(const bf16x8*)&region[32 * w + 16 * p + m][quad * 8];
      ea1[p] = *(const bf16x8*)&region[32 * w + 16 * p + m][32 + quad * 8];
    }
#pragma unroll
    for (int nt = 0; nt < 4; ++nt) {
      bf16x8 b0 = *(const bf16x8*)(pkp + ((size_t)(nt * 2 + 0) * 64 + lane) * 8);
      bf16x8 b1 = *(const bf16x8*)(pkp + ((size_t)(nt * 2 + 1) * 64 + lane) * 8);
      int col = nt * 16 + m;
      float bp2 = b_p2[col];
#pragma unroll
      for (int p = 0; p < 2; ++p) {
        f32x4 acc = {0.f, 0.f, 0.f, 0.f};
        acc = MFMA16(ea0[p], b0, acc);
        acc = MFMA16(ea1[p], b1, acc);
        int g = g0 + 2 * w + p;
        float qv = qkv[(size_t)g * 192 + col];
#pragma unroll
        for (int i = 0; i < 4; ++i) {
          int row = 32 * w + 16 * p + quad * 4 + i;
          int jb = (b << 12) | s_idx[row];
          float kv = qkv[(size_t)jb * 192 + 64 + col];
          region[row][col] = f2bf(qv - kv + acc[i] + bp2);  // s_h
        }
      }
    }
  }

  // v prefetch into registers (latency hidden behind GEMM1/2 below)
  float vreg[2][4][4];
#pragma unroll
  for (int p = 0; p < 2; ++p)
#pragma unroll
    for (int i = 0; i < 4; ++i) {
      int row = 32 * w + 16 * p + quad * 4 + i;
      int jb = (b << 12) | s_idx[row];
      const float* vr = qkv + (size_t)jb * 192 + 128;
#pragma unroll
      for (int nt2 = 0; nt2 < 4; ++nt2) vreg[p][nt2][i] = vr[nt2 * 16 + m];
    }

  // phase4+5: chunked GEMM1 -> s_tc (aliases own s_h rows) -> GEMM2 acc
  bf16x8 ha0[2], ha1[2];
#pragma unroll
  for (int p = 0; p < 2; ++p) {
    ha0[p] = *(const bf16x8*)&region[32 * w + 16 * p + m][quad * 8];
    ha1[p] = *(const bf16x8*)&region[32 * w + 16 * p + m][32 + quad * 8];
  }
  f32x4 acc2[2][4];
#pragma unroll
  for (int p = 0; p < 2; ++p)
#pragma unroll
    for (int nt2 = 0; nt2 < 4; ++nt2) acc2[p][nt2] = (f32x4){0.f, 0.f, 0.f, 0.f};

  unsigned short(*s_tc)[72] = (unsigned short(*)[72])(smem + w * 4608);

#pragma unroll
  for (int c = 0; c < 4; ++c) {
#pragma unroll
    for (int ntc = 0; ntc < 4; ++ntc) {
      int nt = 4 * c + ntc;
      bf16x8 b0 = *(const bf16x8*)(pk1 + ((size_t)(nt * 2 + 0) * 64 + lane) * 8);
      bf16x8 b1 = *(const bf16x8*)(pk1 + ((size_t)(nt * 2 + 1) * 64 + lane) * 8);
      int coll = ntc * 16 + m;
      float ba = b_a1[nt * 16 + m];
#pragma unroll
      for (int p = 0; p < 2; ++p) {
        f32x4 t = {0.f, 0.f, 0.f, 0.f};
        t = MFMA16(ha0[p], b0, t);
        t = MFMA16(ha1[p], b1, t);
#pragma unroll
        for (int i = 0; i < 4; ++i)
          s_tc[16 * p + quad * 4 + i][coll] = f2bf(fmaxf(t[i] + ba, 0.f));
      }
    }
#pragma unroll
    for (int sub = 0; sub < 2; ++sub) {
      int ks = c * 2 + sub;
      bf16x8 a[2];
#pragma unroll
      for (int p = 0; p < 2; ++p)
        a[p] = *(const bf16x8*)&s_tc[16 * p + m][sub * 32 + quad * 8];
#pragma unroll
      for (int nt2 = 0; nt2 < 4; ++nt2) {
        bf16x8 bb =
            *(const bf16x8*)(pk2 + ((size_t)(nt2 * 8 + ks) * 64 + lane) * 8);
#pragma unroll
        for (int p = 0; p < 2; ++p) acc2[p][nt2] = MFMA16(a[p], bb, acc2[p][nt2]);
      }
    }
  }

  // phase6: softmax over k (quad shuffles) + v-weighted sum (v from vreg)
  float ba2[4];
#pragma unroll
  for (int nt2 = 0; nt2 < 4; ++nt2) ba2[nt2] = b_a2[nt2 * 16 + m];
  float aggv[2][4];
#pragma unroll
  for (int p = 0; p < 2; ++p) {
#pragma unroll
    for (int nt2 = 0; nt2 < 4; ++nt2) {
      float sc[4];
#pragma unroll
      for (int i = 0; i < 4; ++i) sc[i] = acc2[p][nt2][i] + ba2[nt2];
      float mx = fmaxf(fmaxf(sc[0], sc[1]), fmaxf(sc[2], sc[3]));
      mx = fmaxf(mx, __shfl_xor(mx, 16));
      mx = fmaxf(mx, __shfl_xor(mx, 32));
      float ex[4], ss = 0.f;
#pragma unroll
      for (int i = 0; i < 4; ++i) {
        ex[i] = exp2f((sc[i] - mx) * 1.4426950408889634f);
        ss += ex[i];
      }
      ss += __shfl_xor(ss, 16);
      ss += __shfl_xor(ss, 32);
      float nu = 0.f;
#pragma unroll
      for (int i = 0; i < 4; ++i) nu = fmaf(ex[i], vreg[p][nt2][i], nu);
      nu += __shfl_xor(nu, 16);
      nu += __shfl_xor(nu, 32);
      aggv[p][nt2] = nu / ss;
    }
  }
  __syncthreads();  // all waves done with region -> reuse for agg/red

  float* s_agg = (float*)smem;  // [8][64]
  if (quad == 0) {
#pragma unroll
    for (int p = 0; p < 2; ++p)
#pragma unroll
      for (int nt2 = 0; nt2 < 4; ++nt2)
        s_agg[(2 * w + p) * 64 + nt2 * 16 + m] = aggv[p][nt2];
  }
  __syncthreads();

  // fc: thread (r=w, c=lane) handles rows w and w+4
  {
    int c = lane, r = w;
    float acc0 = b_fc[c], acc1 = b_fc[c];
    for (int d = 0; d < 64; ++d) {
      float wv = w_fc[d * 64 + c];
      acc0 = fmaf(s_agg[r * 64 + d], wv, acc0);
      acc1 = fmaf(s_agg[(r + 4) * 64 + d], wv, acc1);
    }
    y[(size_t)(g0 + r) * 64 + c] = acc0;
    y[(size_t)(g0 + r + 4) * 64 + c] = acc1;
    float* s_red = (float*)(smem + 2048);
    float* s_red2 = (float*)(smem + 3072);
    s_red[w * 64 + c] = acc0 + acc1;
    s_red2[w * 64 + c] = acc0 * acc0 + acc1 * acc1;
  }
  __syncthreads();
  if (tid < 64) {
    float* s_red = (float*)(smem + 2048);
    float* s_red2 = (float*)(smem + 3072);
    float s = s_red[tid] + s_red[64 + tid] + s_red[128 + tid] + s_red[192 + tid];
    float s2 =
        s_red2[tid] + s_red2[64 + tid] + s_red2[128 + tid] + s_red2[192 + tid];
    atomicAdd(&stats[tid], s);
    atomicAdd(&stats[64 + tid], s2);
  }
}

// ---------------------------------------------------------------------------
// Kernel 3: BN (batch stats) + relu + residual.
// ---------------------------------------------------------------------------
__global__ __launch_bounds__(256) void bn_kernel(
    const float* __restrict__ y, const float* __restrict__ x,
    const float* __restrict__ stats, const float* __restrict__ gamma,
    const float* __restrict__ beta, float* __restrict__ out) {
  size_t o = (size_t)blockIdx.x * 256 + threadIdx.x;
  int c = (int)(o & 63);
  const float inv_n = 1.f / 8192.f;
  float mean = stats[c] * inv_n;
  float var = stats[64 + c] * inv_n - mean * mean;
  float inv = rsqrtf(var + 1e-5f);
  float v = (y[o] - mean) * inv * gamma[c] + beta[c];
  out[o] = fmaxf(v, 0.f) + x[o];
}

// ---------------------------------------------------------------------------
extern "C" void kernel_launch(void* const* d_in, const int* in_sizes, int n_in,
                              void* d_out, int out_size, void* d_ws,
                              size_t ws_size, hipStream_t stream) {
  const float* x = (const float*)d_in[0];
  const float* pos = (const float*)d_in[1];
  const float* w_qkv = (const float*)d_in[2];
  const float* b_qkv = (const float*)d_in[3];
  const float* w_p1 = (const float*)d_in[4];
  const float* b_p1 = (const float*)d_in[5];
  const float* w_p2 = (const float*)d_in[6];
  const float* b_p2 = (const float*)d_in[7];
  const float* w_a1 = (const float*)d_in[8];
  const float* b_a1 = (const float*)d_in[9];
  const float* w_a2 = (const float*)d_in[10];
  const float* b_a2 = (const float*)d_in[11];
  const float* w_fc = (const float*)d_in[12];
  const float* b_fc = (const float*)d_in[13];
  const float* gamma = (const float*)d_in[14];
  const float* beta = (const float*)d_in[15];

  char* ws = (char*)d_ws;
  float* qkv = (float*)(ws + 0);                           // 6291456 B
  float* y = (float*)(ws + 8912896);                       // 2097152 B
  float* stats = (float*)(ws + 11010048);                  // 512 B
  unsigned short* pk1 = (unsigned short*)(ws + 11010560);  // 32768 B
  unsigned short* pk2 = (unsigned short*)(ws + 11043328);  // 32768 B
  unsigned short* pkp = (unsigned short*)(ws + 11076096);  // 8192 B

  hipLaunchKernelGGL(qkv_pack_kernel, dim3(273), dim3(256), 0, stream, x,
                     w_qkv, b_qkv, qkv, w_a1, w_a2, w_p2, pk1, pk2, pkp,
                     stats);
  hipLaunchKernelGGL(fused_kernel, dim3(1024), dim3(256), 0, stream, qkv, pos,
                     pk1, pk2, pkp, w_p1, b_p1, b_p2, b_a1, b_a2, w_fc, b_fc,
                     y, stats);
  hipLaunchKernelGGL(bn_kernel, dim3(2048), dim3(256), 0, stream, y, x, stats,
                     gamma, beta, (float*)d_out);
}

// Round 12
// 148.743 us; speedup vs baseline: 2.0326x; 1.0960x over previous
//
#include <hip/hip_runtime.h>
#include <hip/hip_bf16.h>
#include <math.h>

#define NPTS 4096
#define KNB 16
#define CAP 384
#define QPB 8   // points (=knn queries) per block

typedef __attribute__((ext_vector_type(8))) short bf16x8;
typedef __attribute__((ext_vector_type(4))) float f32x4;
#define MFMA16(a, b, c) __builtin_amdgcn_mfma_f32_16x16x32_bf16(a, b, c, 0, 0, 0)

__device__ __forceinline__ unsigned short f2bf(float f) {
  unsigned int u = __float_as_uint(f);
  unsigned int r = (u + 0x7fffu + ((u >> 16) & 1u)) >> 16;
  return (unsigned short)r;
}

// ---------------------------------------------------------------------------
// Kernel 1 "qkv_pack":
//   blocks [0,128)   qkv = x @ w_qkv + b_qkv via MFMA (64 rows/block, no LDS)
//   blocks [128,272) pack w_a1/w_a2/w_p2 -> bf16 MFMA B-frag order
//   block 272        zero stats
// ---------------------------------------------------------------------------
__global__ __launch_bounds__(256) void qkv_pack_kernel(
    const float* __restrict__ x, const float* __restrict__ w_qkv,
    const float* __restrict__ b_qkv, float* __restrict__ qkv,
    const float* __restrict__ w_a1, const float* __restrict__ w_a2,
    const float* __restrict__ w_p2, unsigned short* __restrict__ pk1,
    unsigned short* __restrict__ pk2, unsigned short* __restrict__ pkp,
    float* __restrict__ stats) {
  int tid = threadIdx.x, bid = blockIdx.x;

  if (bid == 272) {
    if (tid < 128) stats[tid] = 0.f;
    return;
  }
  if (bid >= 128) {
    int e = (bid - 128) * 256 + tid;
    if (e < 16384) {  // w_a1 [64][256]: KS=2, NT=16
      int j = e & 7, lane = (e >> 3) & 63, t = e >> 9;
      int ks = t & 1, nt = t >> 1;
      int k = ks * 32 + ((lane >> 4) << 3) + j, n = nt * 16 + (lane & 15);
      pk1[e] = f2bf(w_a1[k * 256 + n]);
    } else if (e < 32768) {  // w_a2 [256][64]: KS=8, NT=4
      int e2 = e - 16384;
      int j = e2 & 7, lane = (e2 >> 3) & 63, t = e2 >> 9;
      int ks = t & 7, nt = t >> 3;
      int k = ks * 32 + ((lane >> 4) << 3) + j, n = nt * 16 + (lane & 15);
      pk2[e2] = f2bf(w_a2[k * 64 + n]);
    } else if (e < 36864) {  // w_p2 [64][64]: KS=2, NT=4
      int e3 = e - 32768;
      int j = e3 & 7, lane = (e3 >> 3) & 63, t = e3 >> 9;
      int ks = t & 1, nt = t >> 1;
      int k = ks * 32 + ((lane >> 4) << 3) + j, n = nt * 16 + (lane & 15);
      pkp[e3] = f2bf(w_p2[k * 64 + n]);
    }
    return;
  }

  // qkv MFMA: wave w -> rows r0w..r0w+15
  int lane = tid & 63, w = tid >> 6;
  int m = lane & 15, quad = lane >> 4;
  int r0w = bid * 64 + w * 16;

  const float* xr = x + (size_t)(r0w + m) * 64;
  float xa[8], xb[8];
  *(float4*)&xa[0] = *(const float4*)(xr + quad * 8);
  *(float4*)&xa[4] = *(const float4*)(xr + quad * 8 + 4);
  *(float4*)&xb[0] = *(const float4*)(xr + 32 + quad * 8);
  *(float4*)&xb[4] = *(const float4*)(xr + 32 + quad * 8 + 4);
  bf16x8 a0, a1;
#pragma unroll
  for (int j = 0; j < 8; ++j) {
    a0[j] = (short)f2bf(xa[j]);
    a1[j] = (short)f2bf(xb[j]);
  }

#pragma unroll 4
  for (int nt = 0; nt < 12; ++nt) {
    int n = nt * 16 + m;
    int k0 = quad * 8;
    bf16x8 b0, b1;
#pragma unroll
    for (int j = 0; j < 8; ++j) {
      b0[j] = (short)f2bf(w_qkv[(size_t)(k0 + j) * 192 + n]);
      b1[j] = (short)f2bf(w_qkv[(size_t)(32 + k0 + j) * 192 + n]);
    }
    f32x4 acc = {0.f, 0.f, 0.f, 0.f};
    acc = MFMA16(a0, b0, acc);
    acc = MFMA16(a1, b1, acc);
    float bb = b_qkv[n];
#pragma unroll
    for (int i = 0; i < 4; ++i)
      qkv[(size_t)(r0w + quad * 4 + i) * 192 + n] = acc[i] + bb;
  }
}

// ---------------------------------------------------------------------------
// Kernel 2 "fused" (v3): per block = 8 points. One-pass KNN -> s_idx, then
// MFMA attention + fc + stats. LDS ~25.7 KB; v prefetched into 32 VGPRs
// after phase3 (latency hidden behind GEMM1/2).
// __launch_bounds__(256,4): VGPR cap 128 — R11's (256,5) cap of ~102 caused
// wholesale scratch spill (WRITE_SIZE 2.5->67 MB). One-variable fix.
// ---------------------------------------------------------------------------
__global__ __launch_bounds__(256, 4) void fused_kernel(
    const float* __restrict__ qkv, const float* __restrict__ pos,
    const unsigned short* __restrict__ pk1,
    const unsigned short* __restrict__ pk2,
    const unsigned short* __restrict__ pkp, const float* __restrict__ w_p1,
    const float* __restrict__ b_p1, const float* __restrict__ b_p2,
    const float* __restrict__ b_a1, const float* __restrict__ b_a2,
    const float* __restrict__ w_fc, const float* __restrict__ b_fc,
    float* __restrict__ y, float* __restrict__ stats) {
  __shared__ __align__(16) char smem[25216];
  __shared__ int s_idx[128];

  int tid = threadIdx.x, lane = tid & 63, w = tid >> 6;
  int m = lane & 15, quad = lane >> 4;
  int g0 = blockIdx.x * QPB;
  int b = g0 >> 12;
  const float* posb = pos + (size_t)b * NPTS * 3;

  // ======================= KNN phase =======================
  {
    unsigned int(*cbits)[CAP] = (unsigned int(*)[CAP])smem;            // 12288
    int(*cidx)[CAP] = (int(*)[CAP])(smem + 12288);                     // 12288
    unsigned long long* wmin = (unsigned long long*)(smem + 24576);    // 32
    float* sretry = (float*)(smem + 24608);                            // 32
    unsigned int* scnt = (unsigned int*)(smem + 24640);                // 32
    unsigned long long* sprev = (unsigned long long*)(smem + 24672);   // 8
    int* sany = (int*)(smem + 24680);                                  // 4

    float qx[QPB], qy[QPB], qz[QPB];
#pragma unroll
    for (int q = 0; q < QPB; ++q) {
      int i = (g0 + q) & (NPTS - 1);
      qx[q] = posb[i * 3 + 0];
      qy[q] = posb[i * 3 + 1];
      qz[q] = posb[i * 3 + 2];
    }
    if (tid < QPB) scnt[tid] = 0;
    if (tid == 0) sany[0] = 0;
    __syncthreads();

    const float T2 = 0.015625f;  // d < 0.125; expected count ~33
    for (int c = 0; c < NPTS / 256; ++c) {
      int j = c * 256 + tid;
      int j3 = j * 3;
      float px = posb[j3 + 0], py = posb[j3 + 1], pz = posb[j3 + 2];
#pragma unroll
      for (int q = 0; q < QPB; ++q) {
        float dx = qx[q] - px, dy = qy[q] - py, dz = qz[q] - pz;
        float d2 = fmaf(dz, dz, fmaf(dy, dy, dx * dx));
        bool hit = d2 < T2;
        unsigned long long mask = __ballot(hit);
        if (mask) {  // wave-uniform skip (~60% of iterations have no hits)
          if (hit) {
            unsigned int p = atomicAdd(&scnt[q], 1u);
            if (p < CAP) {
              cbits[q][p] = __float_as_uint(d2);
              cidx[q][p] = j;
            }
          }
        }
      }
    }
    __syncthreads();

    if (tid < QPB) {
      int q = tid;
      unsigned int n = scnt[q];
      float nt = 0.f;
      if (n < KNB) nt = 0.0625f;            // widen: d < 0.25
      else if (n > CAP) nt = 0.00390625f;   // narrow: d < 0.0625
      sretry[q] = nt;
      if (nt != 0.f) {
        scnt[q] = 0;
        sany[0] = 1;
      }
    }
    __syncthreads();

    if (sany[0]) {  // rare; block-uniform
      float tr[QPB];
#pragma unroll
      for (int q = 0; q < QPB; ++q) tr[q] = sretry[q];
      for (int c = 0; c < NPTS / 256; ++c) {
        int j = c * 256 + tid;
        int j3 = j * 3;
        float px = posb[j3 + 0], py = posb[j3 + 1], pz = posb[j3 + 2];
#pragma unroll
        for (int q = 0; q < QPB; ++q) {
          if (tr[q] != 0.f) {
            float dx = qx[q] - px, dy = qy[q] - py, dz = qz[q] - pz;
            float d2 = fmaf(dz, dz, fmaf(dy, dy, dx * dx));
            bool hit = d2 < tr[q];
            unsigned long long mask = __ballot(hit);
            if (mask) {
              if (hit) {
                unsigned int p = atomicAdd(&scnt[q], 1u);
                if (p < CAP) {
                  cbits[q][p] = __float_as_uint(d2);
                  cidx[q][p] = j;
                }
              }
            }
          }
        }
      }
      __syncthreads();
    }

    // rank selection -> s_idx[q*16+rank]; wave w handles queries 2w, 2w+1
    for (int qq = 0; qq < 2; ++qq) {
      int q = w * 2 + qq;
      int L = (int)scnt[q];
      if (L >= KNB && L <= CAP) {
        for (int i = lane; i < L; i += 64) {
          unsigned long long ki = ((unsigned long long)cbits[q][i] << 32) |
                                  (unsigned int)cidx[q][i];
          int rank = 0;
          for (int mm = 0; mm < L; ++mm) {
            unsigned long long km = ((unsigned long long)cbits[q][mm] << 32) |
                                    (unsigned int)cidx[q][mm];
            rank += km < ki;
          }
          if (rank < KNB) s_idx[q * KNB + rank] = cidx[q][i];
        }
      }
    }
    __syncthreads();

    // exact fallback (block-uniform branch; pathological only)
    for (int q = 0; q < QPB; ++q) {
      unsigned int n = scnt[q];
      if (n < KNB || n > CAP) {
        unsigned long long prev = 0ull;
        for (int r = 0; r < KNB; ++r) {
          unsigned long long best = ~0ull;
          for (int c = 0; c < NPTS / 256; ++c) {
            int j = c * 256 + tid;
            float dx = qx[q] - posb[j * 3 + 0];
            float dy = qy[q] - posb[j * 3 + 1];
            float dz = qz[q] - posb[j * 3 + 2];
            float d2 = fmaf(dz, dz, fmaf(dy, dy, dx * dx));
            unsigned long long key =
                ((unsigned long long)__float_as_uint(d2) << 32) |
                (unsigned int)j;
            bool ok = (r == 0) || (key > prev);
            best = (ok && key < best) ? key : best;
          }
#pragma unroll
          for (int off = 32; off > 0; off >>= 1) {
            unsigned long long o = __shfl_down(best, off);
            best = best < o ? best : o;
          }
          if (lane == 0) wmin[w] = best;
          __syncthreads();
          if (tid == 0) {
            unsigned long long m0 = wmin[0], m1 = wmin[1];
            unsigned long long m2 = wmin[2], m3 = wmin[3];
            unsigned long long a = m0 < m1 ? m0 : m1;
            unsigned long long d = m2 < m3 ? m2 : m3;
            a = a < d ? a : d;
            s_idx[q * KNB + r] = (int)(unsigned int)a;
            sprev[0] = a;
          }
          __syncthreads();
          prev = sprev[0];
          __syncthreads();
        }
      }
    }
  }
  __syncthreads();  // knn scratch dead; s_idx valid

  // ======================= attention phase =======================
  unsigned short(*region)[72] = (unsigned short(*)[72])smem;        // 18432
  float(*s_rel)[32][3] = (float(*)[32][3])(smem + 18432);           // 1536

  // staging: rel (parallel 32-lane gather)
  if (lane < 32) {
    int row = 32 * w + lane;
    int p = lane >> 4;
    int g = g0 + 2 * w + p;
    int jb = (b << 12) | s_idx[row];
    s_rel[w][lane][0] = pos[(size_t)g * 3 + 0] - pos[(size_t)jb * 3 + 0];
    s_rel[w][lane][1] = pos[(size_t)g * 3 + 1] - pos[(size_t)jb * 3 + 1];
    s_rel[w][lane][2] = pos[(size_t)g * 3 + 2] - pos[(size_t)jb * 3 + 2];
  }

  // phase2: e = relu(rel @ w_p1 + b_p1) -> region (s_e), wave rows
  {
    float w0 = w_p1[lane], w1 = w_p1[64 + lane], w2 = w_p1[128 + lane];
    float bp = b_p1[lane];
    for (int rl = 0; rl < 32; ++rl) {
      int row = 32 * w + rl;
      float rx = s_rel[w][rl][0], ry = s_rel[w][rl][1], rz = s_rel[w][rl][2];
      float e = fmaf(rz, w2, fmaf(ry, w1, fmaf(rx, w0, bp)));
      region[row][lane] = f2bf(fmaxf(e, 0.f));
    }
  }

  // phase3: pe MFMA + h epilogue; s_h overwrites s_e (frags in regs first)
  {
    bf16x8 ea0[2], ea1[2];
#pragma unroll
    for (int p = 0; p < 2; ++p) {
      ea0[p] = *(const bf16x8*)&region[32 * w + 16 * p + m][quad * 8];
      ea1[p] = *(const bf16x8*)&region[32 * w + 16 * p + m][32 + quad * 8];
    }
#pragma unroll
    for (int nt = 0; nt < 4; ++nt) {
      bf16x8 b0 = *(const bf16x8*)(pkp + ((size_t)(nt * 2 + 0) * 64 + lane) * 8);
      bf16x8 b1 = *(const bf16x8*)(pkp + ((size_t)(nt * 2 + 1) * 64 + lane) * 8);
      int col = nt * 16 + m;
      float bp2 = b_p2[col];
#pragma unroll
      for (int p = 0; p < 2; ++p) {
        f32x4 acc = {0.f, 0.f, 0.f, 0.f};
        acc = MFMA16(ea0[p], b0, acc);
        acc = MFMA16(ea1[p], b1, acc);
        int g = g0 + 2 * w + p;
        float qv = qkv[(size_t)g * 192 + col];
#pragma unroll
        for (int i = 0; i < 4; ++i) {
          int row = 32 * w + 16 * p + quad * 4 + i;
          int jb = (b << 12) | s_idx[row];
          float kv = qkv[(size_t)jb * 192 + 64 + col];
          region[row][col] = f2bf(qv - kv + acc[i] + bp2);  // s_h
        }
      }
    }
  }

  // v prefetch into registers (latency hidden behind GEMM1/2 below)
  float vreg[2][4][4];
#pragma unroll
  for (int p = 0; p < 2; ++p)
#pragma unroll
    for (int i = 0; i < 4; ++i) {
      int row = 32 * w + 16 * p + quad * 4 + i;
      int jb = (b << 12) | s_idx[row];
      const float* vr = qkv + (size_t)jb * 192 + 128;
#pragma unroll
      for (int nt2 = 0; nt2 < 4; ++nt2) vreg[p][nt2][i] = vr[nt2 * 16 + m];
    }

  // phase4+5: chunked GEMM1 -> s_tc (aliases own s_h rows) -> GEMM2 acc
  bf16x8 ha0[2], ha1[2];
#pragma unroll
  for (int p = 0; p < 2; ++p) {
    ha0[p] = *(const bf16x8*)&region[32 * w + 16 * p + m][quad * 8];
    ha1[p] = *(const bf16x8*)&region[32 * w + 16 * p + m][32 + quad * 8];
  }
  f32x4 acc2[2][4];
#pragma unroll
  for (int p = 0; p < 2; ++p)
#pragma unroll
    for (int nt2 = 0; nt2 < 4; ++nt2) acc2[p][nt2] = (f32x4){0.f, 0.f, 0.f, 0.f};

  unsigned short(*s_tc)[72] = (unsigned short(*)[72])(smem + w * 4608);

#pragma unroll
  for (int c = 0; c < 4; ++c) {
#pragma unroll
    for (int ntc = 0; ntc < 4; ++ntc) {
      int nt = 4 * c + ntc;
      bf16x8 b0 = *(const bf16x8*)(pk1 + ((size_t)(nt * 2 + 0) * 64 + lane) * 8);
      bf16x8 b1 = *(const bf16x8*)(pk1 + ((size_t)(nt * 2 + 1) * 64 + lane) * 8);
      int coll = ntc * 16 + m;
      float ba = b_a1[nt * 16 + m];
#pragma unroll
      for (int p = 0; p < 2; ++p) {
        f32x4 t = {0.f, 0.f, 0.f, 0.f};
        t = MFMA16(ha0[p], b0, t);
        t = MFMA16(ha1[p], b1, t);
#pragma unroll
        for (int i = 0; i < 4; ++i)
          s_tc[16 * p + quad * 4 + i][coll] = f2bf(fmaxf(t[i] + ba, 0.f));
      }
    }
#pragma unroll
    for (int sub = 0; sub < 2; ++sub) {
      int ks = c * 2 + sub;
      bf16x8 a[2];
#pragma unroll
      for (int p = 0; p < 2; ++p)
        a[p] = *(const bf16x8*)&s_tc[16 * p + m][sub * 32 + quad * 8];
#pragma unroll
      for (int nt2 = 0; nt2 < 4; ++nt2) {
        bf16x8 bb =
            *(const bf16x8*)(pk2 + ((size_t)(nt2 * 8 + ks) * 64 + lane) * 8);
#pragma unroll
        for (int p = 0; p < 2; ++p) acc2[p][nt2] = MFMA16(a[p], bb, acc2[p][nt2]);
      }
    }
  }

  // phase6: softmax over k (quad shuffles) + v-weighted sum (v from vreg)
  float ba2[4];
#pragma unroll
  for (int nt2 = 0; nt2 < 4; ++nt2) ba2[nt2] = b_a2[nt2 * 16 + m];
  float aggv[2][4];
#pragma unroll
  for (int p = 0; p < 2; ++p) {
#pragma unroll
    for (int nt2 = 0; nt2 < 4; ++nt2) {
      float sc[4];
#pragma unroll
      for (int i = 0; i < 4; ++i) sc[i] = acc2[p][nt2][i] + ba2[nt2];
      float mx = fmaxf(fmaxf(sc[0], sc[1]), fmaxf(sc[2], sc[3]));
      mx = fmaxf(mx, __shfl_xor(mx, 16));
      mx = fmaxf(mx, __shfl_xor(mx, 32));
      float ex[4], ss = 0.f;
#pragma unroll
      for (int i = 0; i < 4; ++i) {
        ex[i] = exp2f((sc[i] - mx) * 1.4426950408889634f);
        ss += ex[i];
      }
      ss += __shfl_xor(ss, 16);
      ss += __shfl_xor(ss, 32);
      float nu = 0.f;
#pragma unroll
      for (int i = 0; i < 4; ++i) nu = fmaf(ex[i], vreg[p][nt2][i], nu);
      nu += __shfl_xor(nu, 16);
      nu += __shfl_xor(nu, 32);
      aggv[p][nt2] = nu / ss;
    }
  }
  __syncthreads();  // all waves done with region -> reuse for agg/red

  float* s_agg = (float*)smem;  // [8][64]
  if (quad == 0) {
#pragma unroll
    for (int p = 0; p < 2; ++p)
#pragma unroll
      for (int nt2 = 0; nt2 < 4; ++nt2)
        s_agg[(2 * w + p) * 64 + nt2 * 16 + m] = aggv[p][nt2];
  }
  __syncthreads();

  // fc: thread (r=w, c=lane) handles rows w and w+4
  {
    int c = lane, r = w;
    float acc0 = b_fc[c], acc1 = b_fc[c];
    for (int d = 0; d < 64; ++d) {
      float wv = w_fc[d * 64 + c];
      acc0 = fmaf(s_agg[r * 64 + d], wv, acc0);
      acc1 = fmaf(s_agg[(r + 4) * 64 + d], wv, acc1);
    }
    y[(size_t)(g0 + r) * 64 + c] = acc0;
    y[(size_t)(g0 + r + 4) * 64 + c] = acc1;
    float* s_red = (float*)(smem + 2048);
    float* s_red2 = (float*)(smem + 3072);
    s_red[w * 64 + c] = acc0 + acc1;
    s_red2[w * 64 + c] = acc0 * acc0 + acc1 * acc1;
  }
  __syncthreads();
  if (tid < 64) {
    float* s_red = (float*)(smem + 2048);
    float* s_red2 = (float*)(smem + 3072);
    float s = s_red[tid] + s_red[64 + tid] + s_red[128 + tid] + s_red[192 + tid];
    float s2 =
        s_red2[tid] + s_red2[64 + tid] + s_red2[128 + tid] + s_red2[192 + tid];
    atomicAdd(&stats[tid], s);
    atomicAdd(&stats[64 + tid], s2);
  }
}

// ---------------------------------------------------------------------------
// Kernel 3: BN (batch stats) + relu + residual.
// ---------------------------------------------------------------------------
__global__ __launch_bounds__(256) void bn_kernel(
    const float* __restrict__ y, const float* __restrict__ x,
    const float* __restrict__ stats, const float* __restrict__ gamma,
    const float* __restrict__ beta, float* __restrict__ out) {
  size_t o = (size_t)blockIdx.x * 256 + threadIdx.x;
  int c = (int)(o & 63);
  const float inv_n = 1.f / 8192.f;
  float mean = stats[c] * inv_n;
  float var = stats[64 + c] * inv_n - mean * mean;
  float inv = rsqrtf(var + 1e-5f);
  float v = (y[o] - mean) * inv * gamma[c] + beta[c];
  out[o] = fmaxf(v, 0.f) + x[o];
}

// ---------------------------------------------------------------------------
extern "C" void kernel_launch(void* const* d_in, const int* in_sizes, int n_in,
                              void* d_out, int out_size, void* d_ws,
                              size_t ws_size, hipStream_t stream) {
  const float* x = (const float*)d_in[0];
  const float* pos = (const float*)d_in[1];
  const float* w_qkv = (const float*)d_in[2];
  const float* b_qkv = (const float*)d_in[3];
  const float* w_p1 = (const float*)d_in[4];
  const float* b_p1 = (const float*)d_in[5];
  const float* w_p2 = (const float*)d_in[6];
  const float* b_p2 = (const float*)d_in[7];
  const float* w_a1 = (const float*)d_in[8];
  const float* b_a1 = (const float*)d_in[9];
  const float* w_a2 = (const float*)d_in[10];
  const float* b_a2 = (const float*)d_in[11];
  const float* w_fc = (const float*)d_in[12];
  const float* b_fc = (const float*)d_in[13];
  const float* gamma = (const float*)d_in[14];
  const float* beta = (const float*)d_in[15];

  char* ws = (char*)d_ws;
  float* qkv = (float*)(ws + 0);                           // 6291456 B
  float* y = (float*)(ws + 8912896);                       // 2097152 B
  float* stats = (float*)(ws + 11010048);                  // 512 B
  unsigned short* pk1 = (unsigned short*)(ws + 11010560);  // 32768 B
  unsigned short* pk2 = (unsigned short*)(ws + 11043328);  // 32768 B
  unsigned short* pkp = (unsigned short*)(ws + 11076096);  // 8192 B

  hipLaunchKernelGGL(qkv_pack_kernel, dim3(273), dim3(256), 0, stream, x,
                     w_qkv, b_qkv, qkv, w_a1, w_a2, w_p2, pk1, pk2, pkp,
                     stats);
  hipLaunchKernelGGL(fused_kernel, dim3(1024), dim3(256), 0, stream, qkv, pos,
                     pk1, pk2, pkp, w_p1, b_p1, b_p2, b_a1, b_a2, w_fc, b_fc,
                     y, stats);
  hipLaunchKernelGGL(bn_kernel, dim3(2048), dim3(256), 0, stream, y, x, stats,
                     gamma, beta, (float*)d_out);
}